// Round 1
// baseline (267.809 us; speedup 1.0000x reference)
//
#include <hip/hip_runtime.h>
#include <math.h>

// LRU scan: h[b,t,d] = lam[d]*h[b,t-1,d] + gam[d]*x[b,t,d], inclusive over t.
// lam = exp(-exp(nu_logs)), gam = sqrt(1-lam^2).
// 3-phase chunked scan over the time axis:
//   phase1: per-chunk aggregate (h=0 seed) -> carry[b,c,d]     (reads x once)
//   phase2: exclusive scan of carries along c with coeff lam^L (in-place, tiny)
//   phase3: seeded per-chunk scan, writes output               (re-reads x, L3-hot)

#define B_  4
#define I_  8192
#define D_  1024
#define C_  128           // chunks along time
#define L_  64            // I_ / C_
#define D4  (D_ / 4)      // float4 groups along d

__device__ __forceinline__ void load_lam_gam(const float* __restrict__ nu_logs,
                                             int d4, float4& lam, float4& gam) {
    const float* nl = nu_logs + d4 * 4;
    float nx = expf(nl[0]), ny = expf(nl[1]), nz = expf(nl[2]), nw = expf(nl[3]);
    lam.x = expf(-nx); lam.y = expf(-ny); lam.z = expf(-nz); lam.w = expf(-nw);
    gam.x = sqrtf(1.0f - lam.x * lam.x);
    gam.y = sqrtf(1.0f - lam.y * lam.y);
    gam.z = sqrtf(1.0f - lam.z * lam.z);
    gam.w = sqrtf(1.0f - lam.w * lam.w);
}

__global__ __launch_bounds__(256) void lru_phase1(const float4* __restrict__ x,
                                                  const float* __restrict__ nu_logs,
                                                  float4* __restrict__ carry) {
    int tid = blockIdx.x * 256 + threadIdx.x;     // 0 .. B_*C_*D4-1 = 131071
    int d4 = tid & (D4 - 1);                      // consecutive lanes -> consecutive d (coalesced)
    int c  = (tid >> 8) & (C_ - 1);
    int b  = tid >> 15;

    float4 lam, gam;
    load_lam_gam(nu_logs, d4, lam, gam);

    int idx = (b * I_ + c * L_) * D4 + d4;        // max 33.5M, fits int
    float4 h = {0.f, 0.f, 0.f, 0.f};
#pragma unroll 8
    for (int t = 0; t < L_; ++t) {
        float4 v = x[idx];
        h.x = fmaf(lam.x, h.x, gam.x * v.x);
        h.y = fmaf(lam.y, h.y, gam.y * v.y);
        h.z = fmaf(lam.z, h.z, gam.z * v.z);
        h.w = fmaf(lam.w, h.w, gam.w * v.w);
        idx += D4;
    }
    carry[(b * C_ + c) * D4 + d4] = h;
}

__global__ __launch_bounds__(256) void lru_phase2(const float* __restrict__ nu_logs,
                                                  float4* __restrict__ carry) {
    int tid = blockIdx.x * 256 + threadIdx.x;     // 0 .. B_*D4-1 = 1023
    int d4 = tid & (D4 - 1);
    int b  = tid >> 8;

    const float* nl = nu_logs + d4 * 4;
    float4 lamL;                                  // lam^L = exp(-exp(nu)*L)
    lamL.x = expf(-expf(nl[0]) * (float)L_);
    lamL.y = expf(-expf(nl[1]) * (float)L_);
    lamL.z = expf(-expf(nl[2]) * (float)L_);
    lamL.w = expf(-expf(nl[3]) * (float)L_);

    float4 run = {0.f, 0.f, 0.f, 0.f};
    int base = b * C_ * D4 + d4;
    for (int c = 0; c < C_; ++c) {
        int idx = base + c * D4;
        float4 agg = carry[idx];
        carry[idx] = run;                          // exclusive carry, in-place
        run.x = fmaf(lamL.x, run.x, agg.x);
        run.y = fmaf(lamL.y, run.y, agg.y);
        run.z = fmaf(lamL.z, run.z, agg.z);
        run.w = fmaf(lamL.w, run.w, agg.w);
    }
}

__global__ __launch_bounds__(256) void lru_phase3(const float4* __restrict__ x,
                                                  const float* __restrict__ nu_logs,
                                                  const float4* __restrict__ carry,
                                                  float4* __restrict__ out) {
    int tid = blockIdx.x * 256 + threadIdx.x;
    int d4 = tid & (D4 - 1);
    int c  = (tid >> 8) & (C_ - 1);
    int b  = tid >> 15;

    float4 lam, gam;
    load_lam_gam(nu_logs, d4, lam, gam);

    float4 h = carry[(b * C_ + c) * D4 + d4];     // h_{chunk_start - 1}
    int idx = (b * I_ + c * L_) * D4 + d4;
#pragma unroll 8
    for (int t = 0; t < L_; ++t) {
        float4 v = x[idx];
        h.x = fmaf(lam.x, h.x, gam.x * v.x);
        h.y = fmaf(lam.y, h.y, gam.y * v.y);
        h.z = fmaf(lam.z, h.z, gam.z * v.z);
        h.w = fmaf(lam.w, h.w, gam.w * v.w);
        out[idx] = h;
        idx += D4;
    }
}

extern "C" void kernel_launch(void* const* d_in, const int* in_sizes, int n_in,
                              void* d_out, int out_size, void* d_ws, size_t ws_size,
                              hipStream_t stream) {
    const float4* x       = (const float4*)d_in[0];   // [B, I, D] fp32
    const float*  nu_logs = (const float*)d_in[1];    // [D] fp32
    float4*       out     = (float4*)d_out;           // [B, I, D] fp32
    float4*       carry   = (float4*)d_ws;            // B_*C_*D_ floats = 2 MiB

    dim3 blk(256);
    dim3 grd_big((B_ * C_ * D4) / 256);               // 512 blocks
    dim3 grd_small((B_ * D4) / 256);                  // 4 blocks

    lru_phase1<<<grd_big, blk, 0, stream>>>(x, nu_logs, carry);
    lru_phase2<<<grd_small, blk, 0, stream>>>(nu_logs, carry);
    lru_phase3<<<grd_big, blk, 0, stream>>>(x, nu_logs, carry, out);
}

// Round 2
// 267.744 us; speedup vs baseline: 1.0002x; 1.0002x over previous
//
#include <hip/hip_runtime.h>
#include <math.h>

// LRU scan: h[b,t,d] = lam[d]*h[b,t-1,d] + gam[d]*x[b,t,d], inclusive over t.
// lam = exp(-exp(nu_logs)), gam = sqrt(1-lam^2).
// 3-phase chunked scan over the time axis:
//   phase1: per-chunk aggregate (h=0 seed) -> carry[b,c,d]       (reads x once)
//   phase2: PARALLEL Kogge-Stone scan of carries along c.
//           Decay per chunk is the uniform lam^L, so step-k weight is
//           lam^(L*2^k) via iterative squaring. 8 LDS steps, full parallelism.
//   phase3: seeded per-chunk scan, writes output                 (re-reads x, L3-hot)

#define B_  4
#define I_  8192
#define D_  1024
#define C_  256           // chunks along time (256 -> 16 waves/CU in phases 1/3)
#define L_  32            // I_ / C_
#define D4  (D_ / 4)      // float4 groups along d

__device__ __forceinline__ void load_lam_gam(const float* __restrict__ nu_logs,
                                             int d4, float4& lam, float4& gam) {
    const float* nl = nu_logs + d4 * 4;
    lam.x = expf(-expf(nl[0]));
    lam.y = expf(-expf(nl[1]));
    lam.z = expf(-expf(nl[2]));
    lam.w = expf(-expf(nl[3]));
    gam.x = sqrtf(1.0f - lam.x * lam.x);
    gam.y = sqrtf(1.0f - lam.y * lam.y);
    gam.z = sqrtf(1.0f - lam.z * lam.z);
    gam.w = sqrtf(1.0f - lam.w * lam.w);
}

__global__ __launch_bounds__(256) void lru_phase1(const float4* __restrict__ x,
                                                  const float* __restrict__ nu_logs,
                                                  float4* __restrict__ carry) {
    int tid = blockIdx.x * 256 + threadIdx.x;     // 0 .. B_*C_*D4-1 = 262143
    int d4 = tid & (D4 - 1);                      // consecutive lanes -> consecutive d (coalesced)
    int c  = (tid >> 8) & (C_ - 1);
    int b  = tid >> 16;

    float4 lam, gam;
    load_lam_gam(nu_logs, d4, lam, gam);

    int idx = (b * I_ + c * L_) * D4 + d4;
    float4 h = {0.f, 0.f, 0.f, 0.f};
#pragma unroll 8
    for (int t = 0; t < L_; ++t) {
        float4 v = x[idx];
        h.x = fmaf(lam.x, h.x, gam.x * v.x);
        h.y = fmaf(lam.y, h.y, gam.y * v.y);
        h.z = fmaf(lam.z, h.z, gam.z * v.z);
        h.w = fmaf(lam.w, h.w, gam.w * v.w);
        idx += D4;
    }
    carry[(b * C_ + c) * D4 + d4] = h;
}

// One block per (b, d4); threads = chunk index c. Weighted Kogge-Stone in LDS.
__global__ __launch_bounds__(C_) void lru_phase2(const float* __restrict__ nu_logs,
                                                 float4* __restrict__ carry) {
    __shared__ float4 buf[C_];                    // 4 KiB
    int c  = threadIdx.x;
    int d4 = blockIdx.x & (D4 - 1);
    int b  = blockIdx.x >> 8;

    const float* nl = nu_logs + d4 * 4;
    float4 p;                                     // lam^L, then squared each step
    p.x = expf(-expf(nl[0]) * (float)L_);
    p.y = expf(-expf(nl[1]) * (float)L_);
    p.z = expf(-expf(nl[2]) * (float)L_);
    p.w = expf(-expf(nl[3]) * (float)L_);

    int gidx = (b * C_ + c) * D4 + d4;
    float4 val = carry[gidx];
    buf[c] = val;

    for (int off = 1; off < C_; off <<= 1) {
        __syncthreads();
        float4 prev = (c >= off) ? buf[c - off] : make_float4(0.f, 0.f, 0.f, 0.f);
        __syncthreads();
        if (c >= off) {
            val.x = fmaf(p.x, prev.x, val.x);
            val.y = fmaf(p.y, prev.y, val.y);
            val.z = fmaf(p.z, prev.z, val.z);
            val.w = fmaf(p.w, prev.w, val.w);
            buf[c] = val;
        }
        p.x *= p.x; p.y *= p.y; p.z *= p.z; p.w *= p.w;
    }
    __syncthreads();
    // exclusive carry for chunk c = inclusive prefix of chunk c-1
    float4 excl = (c == 0) ? make_float4(0.f, 0.f, 0.f, 0.f) : buf[c - 1];
    carry[gidx] = excl;
}

__global__ __launch_bounds__(256) void lru_phase3(const float4* __restrict__ x,
                                                  const float* __restrict__ nu_logs,
                                                  const float4* __restrict__ carry,
                                                  float4* __restrict__ out) {
    int tid = blockIdx.x * 256 + threadIdx.x;
    int d4 = tid & (D4 - 1);
    int c  = (tid >> 8) & (C_ - 1);
    int b  = tid >> 16;

    float4 lam, gam;
    load_lam_gam(nu_logs, d4, lam, gam);

    float4 h = carry[(b * C_ + c) * D4 + d4];     // h at chunk start - 1
    int idx = (b * I_ + c * L_) * D4 + d4;
#pragma unroll 8
    for (int t = 0; t < L_; ++t) {
        float4 v = x[idx];
        h.x = fmaf(lam.x, h.x, gam.x * v.x);
        h.y = fmaf(lam.y, h.y, gam.y * v.y);
        h.z = fmaf(lam.z, h.z, gam.z * v.z);
        h.w = fmaf(lam.w, h.w, gam.w * v.w);
        out[idx] = h;
        idx += D4;
    }
}

extern "C" void kernel_launch(void* const* d_in, const int* in_sizes, int n_in,
                              void* d_out, int out_size, void* d_ws, size_t ws_size,
                              hipStream_t stream) {
    const float4* x       = (const float4*)d_in[0];   // [B, I, D] fp32
    const float*  nu_logs = (const float*)d_in[1];    // [D] fp32
    float4*       out     = (float4*)d_out;           // [B, I, D] fp32
    float4*       carry   = (float4*)d_ws;            // B_*C_*D_ floats = 4 MiB

    dim3 blk(256);
    dim3 grd_big((B_ * C_ * D4) / 256);               // 1024 blocks
    dim3 grd_p2(B_ * D4);                             // 1024 blocks (b, d4)

    lru_phase1<<<grd_big, blk, 0, stream>>>(x, nu_logs, carry);
    lru_phase2<<<grd_p2, dim3(C_), 0, stream>>>(nu_logs, carry);
    lru_phase3<<<grd_big, blk, 0, stream>>>(x, nu_logs, carry, out);
}